// Round 11
// baseline (16.605 us; speedup 1.0000x reference)
//
#include <hip/hip_runtime.h>

#define TPB 256
#define NPT 4   // pairs per thread; blocks = total/(TPB*NPT) = 512 at B=16,N=32768

__device__ __forceinline__ float rcpf_(float x) { return __builtin_amdgcn_rcpf(x); }

// Edge-in-parallelogram interval length within [0,1] from the two slab
// crossing-pairs.  min/max sorts entry/exit automatically (no bound-type
// routing); nested fmin/fmax fold to v_min3/v_max3 with inline 1.0/0.0.
__device__ __forceinline__ float slab_len(float ta0, float tb0,
                                          float ta1, float tb1)
{
    const float lo0 = fminf(ta0, tb0), hi0 = fmaxf(ta0, tb0);
    const float lo1 = fminf(ta1, tb1), hi1 = fmaxf(ta1, tb1);
    const float lo  = fmaxf(fmaxf(lo0, lo1), 0.f);
    const float hi  = fminf(fminf(hi0, hi1), 1.f);
    return fmaxf(hi - lo, 0.f);
}

// 1 - IoU for one (pred,gt) rotated-rectangle pair (see round-10 derivation:
// boundary line-integral over 8 edges, parallelogram = 2 slabs, 4 shared
// protected rcps, affine vertex chains).  IoU is invariant to the reference's
// per-image (W*x,H*y) scaling, so image_size is unused.
__device__ __forceinline__ float pair_loss_rect(
    const float4 P01, const float4 P23, const float4 G01, const float4 G23)
{
    float p0x=P01.x, p0y=P01.y, p1x=P01.z, p1y=P01.w;
    float p2x=P23.x, p2y=P23.y, p3x=P23.z, p3y=P23.w;
    float q0x=G01.x, q0y=G01.y, q1x=G01.z, q1y=G01.w;
    float q2x=G23.x, q2y=G23.y, q3x=G23.z, q3y=G23.w;

    float f0x=p1x-p0x, f0y=p1y-p0y, f1x=p2x-p1x, f1y=p2y-p1y;
    float g0x=q1x-q0x, g0y=q1y-q0y, g1x=q2x-q1x, g1y=q2y-q1y;
    float U = f0x*f1y - f0y*f1x;    // 2*areaP for CCW parallelogram
    float T = g0x*g1y - g0y*g1x;

    // _make_quads always emits CCW (U,T = w*h > 0); wave-skipped fixup keeps
    // arbitrary inputs correct at ~zero cost on this data.
    if (__builtin_expect(__any(U < 0.f) || __any(T < 0.f), 0)) {
        if (U < 0.f) { float t;
            t=p0x;p0x=p3x;p3x=t;  t=p0y;p0y=p3y;p3y=t;
            t=p1x;p1x=p2x;p2x=t;  t=p1y;p1y=p2y;p2y=t;
            f0x=p1x-p0x; f0y=p1y-p0y; f1x=p2x-p1x; f1y=p2y-p1y;
            U = f0x*f1y - f0y*f1x;
        }
        if (T < 0.f) { float t;
            t=q0x;q0x=q3x;q3x=t;  t=q0y;q0y=q3y;q3y=t;
            t=q1x;q1x=q2x;q2x=t;  t=q1y;q1y=q2y;q2y=t;
            g0x=q1x-q0x; g0y=q1y-q0y; g1x=q2x-q1x; g1y=q2y-q1y;
            T = g0x*g1y - g0y*g1x;
        }
    }

    // 4 distinct denominators C[k][i] = cross(gk, fi); protect then rcp.
    float C00 = g0x*f0y - g0y*f0x;
    float C01 = g0x*f1y - g0y*f1x;
    float C10 = g1x*f0y - g1y*f0x;
    float C11 = g1x*f1y - g1y*f1x;
    C00 = (fabsf(C00) < 1e-12f) ? 1e-12f : C00;
    C01 = (fabsf(C01) < 1e-12f) ? 1e-12f : C01;
    C10 = (fabsf(C10) < 1e-12f) ? 1e-12f : C10;
    C11 = (fabsf(C11) < 1e-12f) ? 1e-12f : C11;
    const float R00=rcpf_(C00), R01=rcpf_(C01), R10=rcpf_(C10), R11=rcpf_(C11);
    const float TR00=T*R00, TR01=T*R01, TR10=T*R10, TR11=T*R11;
    const float UR00=U*R00, UR01=U*R01, UR10=U*R10, UR11=U*R11;

    // base line-distances at p0/q0 via D = p0 - q0
    const float Dx = p0x-q0x, Dy = p0y-q0y;
    const float cg0D = g0x*Dy - g0y*Dx;
    const float cg1D = g1x*Dy - g1y*Dx;
    const float cf0D = f0x*Dy - f0y*Dx;
    const float cf1D = f1x*Dy - f1y*Dx;
    const float A00 =  cg0D;          // LQ0(p0)
    const float A10 =  cg1D + T;      // LQ1(p0)
    const float B00 = -cf0D;          // LP0(q0)
    const float B10 = -cf1D + U;      // LP1(q0)

    // affine vertex chains (A[k][i+1] = A[k][i] + cross(gk,fi), etc.)
    const float A01=A00+C00, A02=A01+C01, A03=A00+C01;
    const float A11=A10+C10, A12=A11+C11, A13=A10+C11;
    const float B01=B00-C00, B02=B01-C10, B03=B00-C10;
    const float B11=B10-C01, B12=B11-C11, B13=B10-C11;

    // per-edge shoelace weights cross(A,B)
    const float crP0 = p0x*p1y-p0y*p1x, crP1 = p1x*p2y-p1y*p2x;
    const float crP2 = p2x*p3y-p2y*p3x, crP3 = p3x*p0y-p3y*p0x;
    const float crQ0 = q0x*q1y-q0y*q1x, crQ1 = q1x*q2y-q1y*q2x;
    const float crQ2 = q2x*q3y-q2y*q3x, crQ3 = q3x*q0y-q3y*q0x;

    float ta, tc, a2;
    ta = -A00*R00;  tc = -A10*R10;
    a2 = slab_len(ta, ta+TR00, tc, tc+TR10) * crP0;
    ta = -A01*R01;  tc = -A11*R11;
    a2 = fmaf(slab_len(ta, ta+TR01, tc, tc+TR11), crP1, a2);
    ta =  A02*R00;  tc =  A12*R10;
    a2 = fmaf(slab_len(ta, ta-TR00, tc, tc-TR10), crP2, a2);
    ta =  A03*R01;  tc =  A13*R11;
    a2 = fmaf(slab_len(ta, ta-TR01, tc, tc-TR11), crP3, a2);
    ta =  B00*R00;  tc =  B10*R01;
    a2 = fmaf(slab_len(ta, ta-UR00, tc, tc-UR01), crQ0, a2);
    ta =  B01*R10;  tc =  B11*R11;
    a2 = fmaf(slab_len(ta, ta-UR10, tc, tc-UR11), crQ1, a2);
    ta = -B02*R00;  tc = -B12*R01;
    a2 = fmaf(slab_len(ta, ta+UR00, tc, tc+UR01), crQ2, a2);
    ta = -B03*R10;  tc = -B13*R11;
    a2 = fmaf(slab_len(ta, ta+UR10, tc, tc+UR11), crQ3, a2);

    const float inter2 = fabsf(a2);
    const float uni2   = (T + U) + (T + U) - inter2;   // 2(areaP+areaQ)-inter2
    return 1.f - ((uni2 > 0.f) ? inter2 * rcpf_(uni2) : 0.f);
}

// NPT adjacent pairs per thread: halves the workgroup count (ramp cost
// ~5ns/wg measured rounds 8-10) while keeping total issue count constant;
// 4 independent pair computations per thread cover L3 latency at
// 2 waves/SIMD.
__global__ __launch_bounds__(TPB, 2) void obb_pair_kernel(
    const float4* __restrict__ pred, const float4* __restrict__ gt,
    const int* __restrict__ mask, float2* __restrict__ partial, int total)
{
    __shared__ float red_l[TPB / 64], red_m[TPB / 64];

    const int t  = blockIdx.x * TPB + threadIdx.x;
    const int i0 = t * NPT;
    float lacc = 0.f, macc = 0.f;

    if (i0 + NPT - 1 < total) {                    // fast path (all 4 valid)
        const int4 mm = ((const int4*)mask)[t];
        const int mv[NPT] = {mm.x, mm.y, mm.z, mm.w};
        #pragma unroll
        for (int u = 0; u < NPT; ++u) {
            const int i = i0 + u;
            const float4 P0 = pred[2*i], P1 = pred[2*i+1];
            const float4 G0 = gt[2*i],   G1 = gt[2*i+1];
            const float l = pair_loss_rect(P0, P1, G0, G1);
            const float m = (mv[u] != 0) ? 1.f : 0.f;
            lacc = fmaf(l, m, lacc);
            macc += m;
        }
    } else if (i0 < total) {                       // ragged tail
        #pragma unroll
        for (int u = 0; u < NPT; ++u) {
            const int i = i0 + u;
            if (i < total) {
                const float4 P0 = pred[2*i], P1 = pred[2*i+1];
                const float4 G0 = gt[2*i],   G1 = gt[2*i+1];
                const float l = pair_loss_rect(P0, P1, G0, G1);
                const float m = (mask[i] != 0) ? 1.f : 0.f;
                lacc = fmaf(l, m, lacc);
                macc += m;
            }
        }
    }

    // deterministic block reduction: wave shuffle then cross-wave LDS
    float l = lacc, m = macc;
    #pragma unroll
    for (int off = 32; off > 0; off >>= 1) {
        l += __shfl_down(l, off, 64);
        m += __shfl_down(m, off, 64);
    }
    const int wid  = threadIdx.x >> 6;
    const int lane = threadIdx.x & 63;
    if (lane == 0) { red_l[wid] = l; red_m[wid] = m; }
    __syncthreads();
    if (threadIdx.x == 0) {
        const float L = red_l[0] + red_l[1] + red_l[2] + red_l[3];
        const float M = red_m[0] + red_m[1] + red_m[2] + red_m[3];
        partial[blockIdx.x] = make_float2(L, M);
    }
}

// 1024 threads, strided partial loads -> double shuffle-reduce (fixed order).
__global__ __launch_bounds__(1024) void obb_finalize(
    const float2* __restrict__ partial, int nb, float* __restrict__ out)
{
    __shared__ double sl[16], sm[16];
    double l = 0.0, m = 0.0;
    for (int i = threadIdx.x; i < nb; i += 1024) {
        const float2 v = partial[i];
        l += (double)v.x;
        m += (double)v.y;
    }
    #pragma unroll
    for (int off = 32; off > 0; off >>= 1) {
        l += __shfl_down(l, off, 64);
        m += __shfl_down(m, off, 64);
    }
    const int wid  = threadIdx.x >> 6;
    const int lane = threadIdx.x & 63;
    if (lane == 0) { sl[wid] = l; sm[wid] = m; }
    __syncthreads();
    if (threadIdx.x == 0) {
        double L = 0.0, M = 0.0;
        #pragma unroll
        for (int w = 0; w < 16; ++w) { L += sl[w]; M += sm[w]; }
        const double mean = L / (M > 1.0 ? M : 1.0);
        out[0] = (M > 0.0) ? (float)mean : 0.f;
    }
}

extern "C" void kernel_launch(void* const* d_in, const int* in_sizes, int n_in,
                              void* d_out, int out_size, void* d_ws, size_t ws_size,
                              hipStream_t stream)
{
    const float4* pred = (const float4*)d_in[0];   // (B,N,8) f32
    const float4* gt   = (const float4*)d_in[1];   // (B,N,8) f32
    const int* mask    = (const int*)d_in[3];      // (B,N) bool->i32
    float* out = (float*)d_out;                    // scalar f32

    const int total  = in_sizes[0] / 8;            // B*N
    const int blocks = (total + TPB * NPT - 1) / (TPB * NPT);   // 512

    float2* partial = (float2*)d_ws;               // blocks * 8 B

    obb_pair_kernel<<<blocks, TPB, 0, stream>>>(pred, gt, mask, partial, total);
    obb_finalize<<<1, 1024, 0, stream>>>(partial, blocks, out);
}

// Round 12
// 13.818 us; speedup vs baseline: 1.2017x; 1.2017x over previous
//
#include <hip/hip_runtime.h>

#define TPB 256

__device__ __forceinline__ float rcpf_(float x) { return __builtin_amdgcn_rcpf(x); }

// Edge-in-parallelogram interval length within [0,1] from the two slab
// crossing-pairs.  min/max sorts entry/exit automatically; nested fmin/fmax
// fold to v_min3/v_max3 with inline 1.0/0.0.
__device__ __forceinline__ float slab_len(float ta0, float tb0,
                                          float ta1, float tb1)
{
    const float lo0 = fminf(ta0, tb0), hi0 = fmaxf(ta0, tb0);
    const float lo1 = fminf(ta1, tb1), hi1 = fmaxf(ta1, tb1);
    const float lo  = fmaxf(fmaxf(lo0, lo1), 0.f);
    const float hi  = fminf(fminf(hi0, hi1), 1.f);
    return fmaxf(hi - lo, 0.f);
}

// 1 - IoU for one (pred,gt) rotated-rectangle pair (round-10 derivation:
// boundary line-integral over 8 edges, parallelogram = 2 slabs, 4 shared
// protected rcps, affine vertex chains).  IoU is invariant to the reference's
// per-image (W*x,H*y) scaling, so image_size is unused.
__device__ __forceinline__ float pair_loss_rect(
    const float4 P01, const float4 P23, const float4 G01, const float4 G23)
{
    float p0x=P01.x, p0y=P01.y, p1x=P01.z, p1y=P01.w;
    float p2x=P23.x, p2y=P23.y, p3x=P23.z, p3y=P23.w;
    float q0x=G01.x, q0y=G01.y, q1x=G01.z, q1y=G01.w;
    float q2x=G23.x, q2y=G23.y, q3x=G23.z, q3y=G23.w;

    float f0x=p1x-p0x, f0y=p1y-p0y, f1x=p2x-p1x, f1y=p2y-p1y;
    float g0x=q1x-q0x, g0y=q1y-q0y, g1x=q2x-q1x, g1y=q2y-q1y;
    float U = f0x*f1y - f0y*f1x;    // 2*areaP for CCW parallelogram
    float T = g0x*g1y - g0y*g1x;

    // _make_quads always emits CCW (U,T = w*h > 0); wave-skipped fixup keeps
    // arbitrary inputs correct at ~zero cost on this data.
    if (__builtin_expect(__any(U < 0.f) || __any(T < 0.f), 0)) {
        if (U < 0.f) { float t;
            t=p0x;p0x=p3x;p3x=t;  t=p0y;p0y=p3y;p3y=t;
            t=p1x;p1x=p2x;p2x=t;  t=p1y;p1y=p2y;p2y=t;
            f0x=p1x-p0x; f0y=p1y-p0y; f1x=p2x-p1x; f1y=p2y-p1y;
            U = f0x*f1y - f0y*f1x;
        }
        if (T < 0.f) { float t;
            t=q0x;q0x=q3x;q3x=t;  t=q0y;q0y=q3y;q3y=t;
            t=q1x;q1x=q2x;q2x=t;  t=q1y;q1y=q2y;q2y=t;
            g0x=q1x-q0x; g0y=q1y-q0y; g1x=q2x-q1x; g1y=q2y-q1y;
            T = g0x*g1y - g0y*g1x;
        }
    }

    // 4 distinct denominators C[k][i] = cross(gk, fi); protect then rcp.
    float C00 = g0x*f0y - g0y*f0x;
    float C01 = g0x*f1y - g0y*f1x;
    float C10 = g1x*f0y - g1y*f0x;
    float C11 = g1x*f1y - g1y*f1x;
    C00 = (fabsf(C00) < 1e-12f) ? 1e-12f : C00;
    C01 = (fabsf(C01) < 1e-12f) ? 1e-12f : C01;
    C10 = (fabsf(C10) < 1e-12f) ? 1e-12f : C10;
    C11 = (fabsf(C11) < 1e-12f) ? 1e-12f : C11;
    const float R00=rcpf_(C00), R01=rcpf_(C01), R10=rcpf_(C10), R11=rcpf_(C11);
    const float TR00=T*R00, TR01=T*R01, TR10=T*R10, TR11=T*R11;
    const float UR00=U*R00, UR01=U*R01, UR10=U*R10, UR11=U*R11;

    // base line-distances at p0/q0 via D = p0 - q0
    const float Dx = p0x-q0x, Dy = p0y-q0y;
    const float cg0D = g0x*Dy - g0y*Dx;
    const float cg1D = g1x*Dy - g1y*Dx;
    const float cf0D = f0x*Dy - f0y*Dx;
    const float cf1D = f1x*Dy - f1y*Dx;
    const float A00 =  cg0D;          // LQ0(p0)
    const float A10 =  cg1D + T;      // LQ1(p0)
    const float B00 = -cf0D;          // LP0(q0)
    const float B10 = -cf1D + U;      // LP1(q0)

    // affine vertex chains (A[k][i+1] = A[k][i] + cross(gk,fi), etc.)
    const float A01=A00+C00, A02=A01+C01, A03=A00+C01;
    const float A11=A10+C10, A12=A11+C11, A13=A10+C11;
    const float B01=B00-C00, B02=B01-C10, B03=B00-C10;
    const float B11=B10-C01, B12=B11-C11, B13=B10-C11;

    // per-edge shoelace weights cross(A,B)
    const float crP0 = p0x*p1y-p0y*p1x, crP1 = p1x*p2y-p1y*p2x;
    const float crP2 = p2x*p3y-p2y*p3x, crP3 = p3x*p0y-p3y*p0x;
    const float crQ0 = q0x*q1y-q0y*q1x, crQ1 = q1x*q2y-q1y*q2x;
    const float crQ2 = q2x*q3y-q2y*q3x, crQ3 = q3x*q0y-q3y*q0x;

    float ta, tc, a2;
    ta = -A00*R00;  tc = -A10*R10;
    a2 = slab_len(ta, ta+TR00, tc, tc+TR10) * crP0;
    ta = -A01*R01;  tc = -A11*R11;
    a2 = fmaf(slab_len(ta, ta+TR01, tc, tc+TR11), crP1, a2);
    ta =  A02*R00;  tc =  A12*R10;
    a2 = fmaf(slab_len(ta, ta-TR00, tc, tc-TR10), crP2, a2);
    ta =  A03*R01;  tc =  A13*R11;
    a2 = fmaf(slab_len(ta, ta-TR01, tc, tc-TR11), crP3, a2);
    ta =  B00*R00;  tc =  B10*R01;
    a2 = fmaf(slab_len(ta, ta-UR00, tc, tc-UR01), crQ0, a2);
    ta =  B01*R10;  tc =  B11*R11;
    a2 = fmaf(slab_len(ta, ta-UR10, tc, tc-UR11), crQ1, a2);
    ta = -B02*R00;  tc = -B12*R01;
    a2 = fmaf(slab_len(ta, ta+UR00, tc, tc+UR01), crQ2, a2);
    ta = -B03*R10;  tc = -B13*R11;
    a2 = fmaf(slab_len(ta, ta+UR10, tc, tc+UR11), crQ3, a2);

    const float inter2 = fabsf(a2);
    const float uni2   = (T + U) + (T + U) - inter2;   // 2(areaP+areaQ)-inter2
    return 1.f - ((uni2 > 0.f) ? inter2 * rcpf_(uni2) : 0.f);
}

// 1 pair/thread, 2048 workgroups -> up to 8 blocks/CU resident (max TLP).
// launch_bounds(256,8) caps VGPR at 64 (select-variant measured 40 at R8,
// slab is leaner) so occupancy reaches 8 waves/SIMD.
__global__ __launch_bounds__(TPB, 8) void obb_pair_kernel(
    const float4* __restrict__ pred, const float4* __restrict__ gt,
    const int* __restrict__ mask, float2* __restrict__ partial, int total)
{
    __shared__ float red_l[TPB / 64], red_m[TPB / 64];

    const int idx = blockIdx.x * TPB + threadIdx.x;
    float lacc = 0.f, macc = 0.f;

    if (idx < total) {
        const float4 P0 = pred[2*idx], P1 = pred[2*idx+1];
        const float4 G0 = gt[2*idx],   G1 = gt[2*idx+1];
        const float m = (mask[idx] != 0) ? 1.f : 0.f;
        lacc = pair_loss_rect(P0, P1, G0, G1) * m;
        macc = m;
    }

    // deterministic block reduction: wave shuffle then cross-wave LDS
    float l = lacc, m = macc;
    #pragma unroll
    for (int off = 32; off > 0; off >>= 1) {
        l += __shfl_down(l, off, 64);
        m += __shfl_down(m, off, 64);
    }
    const int wid  = threadIdx.x >> 6;
    const int lane = threadIdx.x & 63;
    if (lane == 0) { red_l[wid] = l; red_m[wid] = m; }
    __syncthreads();
    if (threadIdx.x == 0) {
        const float L = red_l[0] + red_l[1] + red_l[2] + red_l[3];
        const float M = red_m[0] + red_m[1] + red_m[2] + red_m[3];
        partial[blockIdx.x] = make_float2(L, M);
    }
}

// 1024 threads; each loads one float4 (= 2 partials) -> double shuffle-reduce
// in fixed order (deterministic), cross-wave via LDS.
__global__ __launch_bounds__(1024) void obb_finalize(
    const float4* __restrict__ partial4, int nb4, float* __restrict__ out)
{
    __shared__ double sl[16], sm[16];
    double l = 0.0, m = 0.0;
    for (int i = threadIdx.x; i < nb4; i += 1024) {
        const float4 v = partial4[i];
        l += (double)v.x + (double)v.z;
        m += (double)v.y + (double)v.w;
    }
    #pragma unroll
    for (int off = 32; off > 0; off >>= 1) {
        l += __shfl_down(l, off, 64);
        m += __shfl_down(m, off, 64);
    }
    const int wid  = threadIdx.x >> 6;
    const int lane = threadIdx.x & 63;
    if (lane == 0) { sl[wid] = l; sm[wid] = m; }
    __syncthreads();
    if (threadIdx.x == 0) {
        double L = 0.0, M = 0.0;
        #pragma unroll
        for (int w = 0; w < 16; ++w) { L += sl[w]; M += sm[w]; }
        const double mean = L / (M > 1.0 ? M : 1.0);
        out[0] = (M > 0.0) ? (float)mean : 0.f;
    }
}

extern "C" void kernel_launch(void* const* d_in, const int* in_sizes, int n_in,
                              void* d_out, int out_size, void* d_ws, size_t ws_size,
                              hipStream_t stream)
{
    const float4* pred = (const float4*)d_in[0];   // (B,N,8) f32
    const float4* gt   = (const float4*)d_in[1];   // (B,N,8) f32
    const int* mask    = (const int*)d_in[3];      // (B,N) bool->i32
    float* out = (float*)d_out;                    // scalar f32

    const int total  = in_sizes[0] / 8;            // B*N = 524288
    const int blocks = (total + TPB - 1) / TPB;    // 2048

    float2* partial = (float2*)d_ws;               // blocks * 8 B

    obb_pair_kernel<<<blocks, TPB, 0, stream>>>(pred, gt, mask, partial, total);
    obb_finalize<<<1, 1024, 0, stream>>>((const float4*)partial, blocks / 2, out);
}